// Round 6
// baseline (63.275 us; speedup 1.0000x reference)
//
#include <hip/hip_runtime.h>

// PCEN: x[B,1,C,T] fp32 -> out[B,C,T] fp32
// EMA along T (first-order linear recurrence), parallelized via affine-scan.
// PER=8 / 1024 threads; non-temporal output stores keep the 128 MiB input
// L3-resident (output is write-once-never-read).

#define EPSC 1e-6f

// fast HW transcendentals (v_exp_f32 = 2^x, v_log_f32 = log2 x)
#define EXP2F(x) __builtin_amdgcn_exp2f(x)
#define LOG2F(x) __builtin_amdgcn_logf(x)

typedef float f32x4 __attribute__((ext_vector_type(4)));

constexpr int Cc = 128;
constexpr int Tc = 8192;
constexpr int THREADS = 1024;
constexpr int PER = Tc / THREADS;      // 8 elements per thread
constexpr int VEC = PER / 4;           // 2 float4 per thread
constexpr int NWAVES = THREADS / 64;   // 16

__global__ __launch_bounds__(THREADS) void pcen_kernel(
    const float* __restrict__ x,
    const float* __restrict__ alpha,
    const float* __restrict__ delta,
    const float* __restrict__ root,
    const float* __restrict__ emaw,
    float* __restrict__ out)
{
    const int row  = blockIdx.x;        // b*C + c
    const int c    = row & (Cc - 1);
    const int tid  = threadIdx.x;
    const int lane = tid & 63;
    const int wid  = tid >> 6;

    // per-channel params (uniform within block)
    const float wgt = fminf(fmaxf(emaw[c], 0.0f), 0.2f);
    const float om  = 1.0f - wgt;
    const float a   = fminf(alpha[c], 1.0f);
    const float r   = fmaxf(root[c], 1.0f);
    const float oor = 1.0f / r;
    const float dl  = delta[c];
    const float dpow = EXP2F(oor * LOG2F(dl));   // delta^(1/r), delta>0

    const size_t base = (size_t)row * Tc + (size_t)tid * PER;
    const f32x4* xin = reinterpret_cast<const f32x4*>(x + base);

    f32x4 xr[VEC];
    #pragma unroll
    for (int v = 0; v < VEC; ++v) xr[v] = xin[v];

    // ---- pass 1: local affine composition of the chunk ----
    // state_out = Q * state_in + P ; thread 0 seeds with x[0] (== res[0]=x[0]) and Q=0
    float s = (tid == 0) ? xr[0].x : 0.0f;
    #pragma unroll
    for (int v = 0; v < VEC; ++v) {
        s = fmaf(wgt, xr[v].x, om * s);
        s = fmaf(wgt, xr[v].y, om * s);
        s = fmaf(wgt, xr[v].z, om * s);
        s = fmaf(wgt, xr[v].w, om * s);
    }
    const float om2 = om * om, om4 = om2 * om2;
    float Q = (tid == 0) ? 0.0f : om4 * om4;    // (1-w)^8
    float P = s;

    // ---- wave-level inclusive scan (non-commutative compose) ----
    #pragma unroll
    for (int d = 1; d < 64; d <<= 1) {
        float Qu = __shfl_up(Q, (unsigned)d);
        float Pu = __shfl_up(P, (unsigned)d);
        if (lane >= d) { P = fmaf(Q, Pu, P); Q = Q * Qu; }
    }

    // ---- cross-wave scan via LDS ----
    __shared__ float sQ[NWAVES], sP[NWAVES];
    if (lane == 63) { sQ[wid] = Q; sP[wid] = P; }
    __syncthreads();

    float Pw = 0.0f;                    // composed actual state of waves 0..wid-1
    #pragma unroll
    for (int i = 0; i < NWAVES - 1; ++i) {
        if (i < wid) Pw = fmaf(sQ[i], Pw, sP[i]);
    }

    // lane-exclusive prefix within wave
    float Qe = __shfl_up(Q, 1u);
    float Pe = __shfl_up(P, 1u);
    if (lane == 0) { Qe = 1.0f; Pe = 0.0f; }

    // incoming state for this thread (waves-before, then lanes-before applied)
    float s_in = fmaf(Qe, Pw, Pe);

    // ---- pass 2: exact EMA recompute + pointwise PCEN ----
    s = (tid == 0) ? xr[0].x : s_in;
    #pragma unroll
    for (int v = 0; v < VEC; ++v) {
        f32x4 xv = xr[v];
        {
            const float xx = xv.x;
            s = fmaf(wgt, xx, om * s);
            const float p = EXP2F(-a * LOG2F(EPSC + s));
            xv.x = EXP2F(oor * LOG2F(fmaf(xx, p, dl))) - dpow;
        }
        {
            const float xx = xv.y;
            s = fmaf(wgt, xx, om * s);
            const float p = EXP2F(-a * LOG2F(EPSC + s));
            xv.y = EXP2F(oor * LOG2F(fmaf(xx, p, dl))) - dpow;
        }
        {
            const float xx = xv.z;
            s = fmaf(wgt, xx, om * s);
            const float p = EXP2F(-a * LOG2F(EPSC + s));
            xv.z = EXP2F(oor * LOG2F(fmaf(xx, p, dl))) - dpow;
        }
        {
            const float xx = xv.w;
            s = fmaf(wgt, xx, om * s);
            const float p = EXP2F(-a * LOG2F(EPSC + s));
            xv.w = EXP2F(oor * LOG2F(fmaf(xx, p, dl))) - dpow;
        }
        xr[v] = xv;
    }

    // non-temporal stores: output is never re-read; don't pollute L2/L3
    f32x4* orow = reinterpret_cast<f32x4*>(out + base);
    #pragma unroll
    for (int v = 0; v < VEC; ++v) {
        __builtin_nontemporal_store(xr[v], orow + v);
    }
}

extern "C" void kernel_launch(void* const* d_in, const int* in_sizes, int n_in,
                              void* d_out, int out_size, void* d_ws, size_t ws_size,
                              hipStream_t stream) {
    const float* x     = (const float*)d_in[0];
    const float* alpha = (const float*)d_in[1];
    const float* delta = (const float*)d_in[2];
    const float* root  = (const float*)d_in[3];
    const float* emaw  = (const float*)d_in[4];
    float* out = (float*)d_out;

    const int rows = in_sizes[0] / Tc;  // B*C = 4096
    pcen_kernel<<<rows, THREADS, 0, stream>>>(x, alpha, delta, root, emaw, out);
}

// Round 7
// 44.903 us; speedup vs baseline: 1.4092x; 1.4092x over previous
//
#include <hip/hip_runtime.h>

// PCEN: x[B,1,C,T] fp32 -> out[B,C,T] fp32
// EMA along T via affine-scan. PER=8 / 1024 threads.
// Output: lane-redistributed via __shfl so each nt store instruction writes
// a fully-contiguous 1024B wave span (no partial-line nt writes).

#define EPSC 1e-6f

#define EXP2F(x) __builtin_amdgcn_exp2f(x)
#define LOG2F(x) __builtin_amdgcn_logf(x)

typedef float f32x4 __attribute__((ext_vector_type(4)));

constexpr int Cc = 128;
constexpr int Tc = 8192;
constexpr int THREADS = 1024;
constexpr int PER = Tc / THREADS;      // 8 elements per thread
constexpr int VEC = PER / 4;           // 2 float4 per thread
constexpr int NWAVES = THREADS / 64;   // 16

__device__ inline f32x4 shfl4(f32x4 v, int src) {
    f32x4 r;
    r.x = __shfl(v.x, src);
    r.y = __shfl(v.y, src);
    r.z = __shfl(v.z, src);
    r.w = __shfl(v.w, src);
    return r;
}

__global__ __launch_bounds__(THREADS) void pcen_kernel(
    const float* __restrict__ x,
    const float* __restrict__ alpha,
    const float* __restrict__ delta,
    const float* __restrict__ root,
    const float* __restrict__ emaw,
    float* __restrict__ out)
{
    const int row  = blockIdx.x;        // b*C + c
    const int c    = row & (Cc - 1);
    const int tid  = threadIdx.x;
    const int lane = tid & 63;
    const int wid  = tid >> 6;

    // per-channel params (uniform within block)
    const float wgt = fminf(fmaxf(emaw[c], 0.0f), 0.2f);
    const float om  = 1.0f - wgt;
    const float a   = fminf(alpha[c], 1.0f);
    const float r   = fmaxf(root[c], 1.0f);
    const float oor = 1.0f / r;
    const float dl  = delta[c];
    const float dpow = EXP2F(oor * LOG2F(dl));   // delta^(1/r), delta>0

    const size_t base = (size_t)row * Tc + (size_t)tid * PER;
    const f32x4* xin = reinterpret_cast<const f32x4*>(x + base);

    f32x4 xr[VEC];
    #pragma unroll
    for (int v = 0; v < VEC; ++v) xr[v] = xin[v];

    // ---- pass 1: local affine composition of the chunk ----
    // state_out = Q * state_in + P ; thread 0 seeds with x[0] (== res[0]=x[0]) and Q=0
    float s = (tid == 0) ? xr[0].x : 0.0f;
    #pragma unroll
    for (int v = 0; v < VEC; ++v) {
        s = fmaf(wgt, xr[v].x, om * s);
        s = fmaf(wgt, xr[v].y, om * s);
        s = fmaf(wgt, xr[v].z, om * s);
        s = fmaf(wgt, xr[v].w, om * s);
    }
    const float om2 = om * om, om4 = om2 * om2;
    float Q = (tid == 0) ? 0.0f : om4 * om4;    // (1-w)^8
    float P = s;

    // ---- wave-level inclusive scan (non-commutative compose) ----
    #pragma unroll
    for (int d = 1; d < 64; d <<= 1) {
        float Qu = __shfl_up(Q, (unsigned)d);
        float Pu = __shfl_up(P, (unsigned)d);
        if (lane >= d) { P = fmaf(Q, Pu, P); Q = Q * Qu; }
    }

    // ---- cross-wave scan via LDS ----
    __shared__ float sQ[NWAVES], sP[NWAVES];
    if (lane == 63) { sQ[wid] = Q; sP[wid] = P; }
    __syncthreads();

    float Pw = 0.0f;                    // composed actual state of waves 0..wid-1
    #pragma unroll
    for (int i = 0; i < NWAVES - 1; ++i) {
        if (i < wid) Pw = fmaf(sQ[i], Pw, sP[i]);
    }

    // lane-exclusive prefix within wave
    float Qe = __shfl_up(Q, 1u);
    float Pe = __shfl_up(P, 1u);
    if (lane == 0) { Qe = 1.0f; Pe = 0.0f; }

    // incoming state for this thread (waves-before, then lanes-before applied)
    float s_in = fmaf(Qe, Pw, Pe);

    // ---- pass 2: exact EMA recompute + pointwise PCEN ----
    s = (tid == 0) ? xr[0].x : s_in;
    #pragma unroll
    for (int v = 0; v < VEC; ++v) {
        f32x4 xv = xr[v];
        {
            const float xx = xv.x;
            s = fmaf(wgt, xx, om * s);
            const float p = EXP2F(-a * LOG2F(EPSC + s));
            xv.x = EXP2F(oor * LOG2F(fmaf(xx, p, dl))) - dpow;
        }
        {
            const float xx = xv.y;
            s = fmaf(wgt, xx, om * s);
            const float p = EXP2F(-a * LOG2F(EPSC + s));
            xv.y = EXP2F(oor * LOG2F(fmaf(xx, p, dl))) - dpow;
        }
        {
            const float xx = xv.z;
            s = fmaf(wgt, xx, om * s);
            const float p = EXP2F(-a * LOG2F(EPSC + s));
            xv.z = EXP2F(oor * LOG2F(fmaf(xx, p, dl))) - dpow;
        }
        {
            const float xx = xv.w;
            s = fmaf(wgt, xx, om * s);
            const float p = EXP2F(-a * LOG2F(EPSC + s));
            xv.w = EXP2F(oor * LOG2F(fmaf(xx, p, dl))) - dpow;
        }
        xr[v] = xv;
    }

    // ---- lane-redistributed, fully-coalesced non-temporal stores ----
    // Wave covers 512 floats at wave_base. Store instr k: lane l writes
    // float4 at wave_base + k*256 + l*4, which is register-half (l&1) of
    // lane (k*32 + l/2). Each instruction covers 1024B contiguous.
    const size_t wave_base = (size_t)row * Tc + (size_t)wid * 512;
    float* orow = out + wave_base;
    #pragma unroll
    for (int k = 0; k < 2; ++k) {
        const int src = k * 32 + (lane >> 1);
        f32x4 a0 = shfl4(xr[0], src);
        f32x4 b0 = shfl4(xr[1], src);
        f32x4 w0 = (lane & 1) ? b0 : a0;
        __builtin_nontemporal_store(
            w0, reinterpret_cast<f32x4*>(orow + k * 256 + lane * 4));
    }
}

extern "C" void kernel_launch(void* const* d_in, const int* in_sizes, int n_in,
                              void* d_out, int out_size, void* d_ws, size_t ws_size,
                              hipStream_t stream) {
    const float* x     = (const float*)d_in[0];
    const float* alpha = (const float*)d_in[1];
    const float* delta = (const float*)d_in[2];
    const float* root  = (const float*)d_in[3];
    const float* emaw  = (const float*)d_in[4];
    float* out = (float*)d_out;

    const int rows = in_sizes[0] / Tc;  // B*C = 4096
    pcen_kernel<<<rows, THREADS, 0, stream>>>(x, alpha, delta, root, emaw, out);
}